// Round 7
// baseline (59.980 us; speedup 1.0000x reference)
//
#include <hip/hip_runtime.h>
#include <cmath>
#include <complex>
#include <algorithm>

// ---------------- compile-time path metadata ----------------
#define NPATH 15
constexpr int PL1[NPATH] = {0,0,0, 1,1,1,1,1,1, 2,2,2,2,2,2};
constexpr int PL2[NPATH] = {0,1,2, 0,1,1,1,2,2, 0,1,1,2,2,2};
constexpr int PL3[NPATH] = {0,1,2, 1,0,1,2,1,2, 2,1,2,0,1,2};
constexpr int CGOFF[NPATH] = {0,1,10,35,44,53,80,125,170,245,270,315,390,415,490};
constexpr int CGTOT = 615;
constexpr int YOFF[3] = {0,1,4};
constexpr int KKB[3]  = {0,1,4};  // acc k-base per l3

// general (non-delta) paths: 5:(1,1,1) 6:(1,1,2) 7:(1,2,1) 8:(1,2,2) 10:(2,1,1) 11:(2,1,2) 13:(2,2,1) 14:(2,2,2)
constexpr int GB[8] = {0,9,24,33,48,63,88,103};   // cumsum of D1*D3: 9,15,9,15,15,25,15,25
constexpr int YGTOT = 137;                        // 128 general yc entries + 9 raw y
// s_yg layout (per tile): entry e, row n -> s_yg[e*16 + n]; raw y[j] at entry 128+j

struct CGArg { float v[CGTOT]; }; // alpha-folded real-basis CG (kernarg -> SGPR-resident constants)

// ---------------- host: exact port of reference CG construction ----------------
static double factd(int n){ double r=1.0; for(int i=2;i<=n;++i) r*=(double)i; return r; }

static double su2_cg(int j1,int m1,int j2,int m2,int j3,int m3){
  if (m3 != m1+m2) return 0.0;
  double c = (double)(2*j3+1) * factd(j1+j2-j3) * factd(j1-j2+j3) * factd(-j1+j2+j3)
             / factd(j1+j2+j3+1);
  c = std::sqrt(c);
  c *= std::sqrt(factd(j3+m3)*factd(j3-m3)*factd(j1-m1)*factd(j1+m1)*factd(j2-m2)*factd(j2+m2));
  double s = 0.0;
  int kmin = std::max(0, std::max(j2-j3-m1, j1-j3+m2));
  int kmax = std::min(j1+j2-j3, std::min(j1-m1, j2+m2));
  for (int k=kmin;k<=kmax;++k){
    double d = factd(k)*factd(j1+j2-j3-k)*factd(j1-m1-k)*factd(j2+m2-k)
             * factd(j3-j2+m1+k)*factd(j3-j1-m2+k);
    s += ((k&1)? -1.0 : 1.0)/d;
  }
  return c*s;
}

static void qmat(int l, std::complex<double>* q){
  int d = 2*l+1;
  for (int a=0;a<d*d;++a) q[a] = std::complex<double>(0.0,0.0);
  const double r2 = 1.0/std::sqrt(2.0);
  for (int m=-l; m<0; ++m){
    q[(l+m)*d + (l-m)] = std::complex<double>(r2, 0.0);
    q[(l+m)*d + (l+m)] = std::complex<double>(0.0, -r2);
  }
  q[l*d + l] = std::complex<double>(1.0,0.0);
  for (int m=1; m<=l; ++m){
    double sg = (m&1)? -1.0 : 1.0;
    q[(l+m)*d + (l+m)] = std::complex<double>(sg*r2, 0.0);
    q[(l+m)*d + (l-m)] = std::complex<double>(0.0, sg*r2);
  }
  std::complex<double> ph = (l==0)? std::complex<double>(1,0)
                        : (l==1)? std::complex<double>(0,-1)
                                : std::complex<double>(-1,0);   // (-i)^l
  for (int a=0;a<d*d;++a) q[a] *= ph;
}

static void compute_cg(float* outv){
  const int npaths_to[3] = {3,6,6};
  for (int p=0;p<NPATH;++p){
    int l1=PL1[p], l2=PL2[p], l3=PL3[p];
    int d1=2*l1+1, d2=2*l2+1, d3=2*l3+1;
    std::complex<double> C[5][5][5];
    for (int a=0;a<5;++a) for(int b=0;b<5;++b) for(int c=0;c<5;++c) C[a][b][c]=std::complex<double>(0,0);
    for (int m1=-l1;m1<=l1;++m1) for (int m2=-l2;m2<=l2;++m2){
      int m3=m1+m2;
      if (std::abs(m3)<=l3) C[l1+m1][l2+m2][l3+m3] = su2_cg(l1,m1,l2,m2,l3,m3);
    }
    std::complex<double> U1[25],U2[25],U3[25];
    qmat(l1,U1); qmat(l2,U2); qmat(l3,U3);
    double Cr[5][5][5]; double nrm=0.0;
    for (int a=0;a<d1;++a) for (int b=0;b<d2;++b) for (int c=0;c<d3;++c){
      std::complex<double> s(0,0);
      for (int i=0;i<d1;++i) for (int j=0;j<d2;++j) for (int k=0;k<d3;++k)
        s += U1[i*d1+a]*U2[j*d2+b]*std::conj(U3[k*d3+c])*C[i][j][k];
      Cr[a][b][c] = s.real();
      nrm += s.real()*s.real();
    }
    nrm = std::sqrt(nrm);
    double alpha = 1.0/std::sqrt(64.0*(double)npaths_to[l3]);
    float* o = outv + CGOFF[p];
    int idx=0;
    for (int a=0;a<d1;++a) for (int b=0;b<d2;++b) for (int c=0;c<d3;++c)
      o[idx++] = (float)(Cr[a][b][c]/nrm*alpha);
  }
}

// ---------------- device ----------------
typedef short bf16x8 __attribute__((ext_vector_type(8)));
typedef float f32x4 __attribute__((ext_vector_type(4)));

__device__ __forceinline__ unsigned cvtpk_bf16(float a, float b){
  unsigned r;
  asm("v_cvt_pk_bf16_f32 %0, %1, %2" : "=v"(r) : "v"(a), "v"(b));
  return r;   // lo16 = bf16(a), hi16 = bf16(b)
}

// A-fragment: lane (cl,q) holds A[row=cl][u=kt*32+q*8 ..+7]; XOR-swizzled 16B chunks (R2-verified)
__device__ __forceinline__ bf16x8 afrag(const unsigned short* s_xt, int plane, int kt, int row, int q){
  int c = (kt*4 + q) ^ (row & 7);
  return *reinterpret_cast<const bf16x8*>(s_xt + (plane*16 + row)*64 + c*8);
}
// B-fragment: lane (cl,q) holds B[u=kt*32+q*8..+7][w=wt*16+cl] from WT[p][w][u]
__device__ __forceinline__ bf16x8 wfrag(const unsigned short* WT, int p, int wt, int cl, int kt, int q){
  return *reinterpret_cast<const bf16x8*>(WT + p*4096 + (wt*16+cl)*64 + kt*32 + q*8);
}
// xT write of one packed u-quad (swizzle matches afrag)
__device__ __forceinline__ void xt_write_pk(unsigned short* s_xt, int plane, int n, int t16, uint2 pk){
  const int swz = (((t16>>1)^(n&7))<<3) + ((t16&1)<<2);
  *reinterpret_cast<uint2*>(s_xt + (plane*16 + n)*64 + swz) = pk;
}

// pack this thread's x registers (f32) into 9 packed bf16 u-quads (one per plane)
__device__ __forceinline__ void pack_x(const float4& r0, const float4* r1, const float4* r2, uint2* xpk){
  const float* f0 = reinterpret_cast<const float*>(&r0);   // 4:  x[t16*4+uu]
  const float* f1 = reinterpret_cast<const float*>(r1);    // 12: x[64 + (4t16+uu)*3 + i]
  const float* f2 = reinterpret_cast<const float*>(r2);    // 20: x[256 + (4t16+uu)*5 + i]
  xpk[0].x = cvtpk_bf16(f0[0], f0[1]);  xpk[0].y = cvtpk_bf16(f0[2], f0[3]);
  #pragma unroll
  for (int i=0;i<3;++i){
    xpk[1+i].x = cvtpk_bf16(f1[0*3+i], f1[1*3+i]);
    xpk[1+i].y = cvtpk_bf16(f1[2*3+i], f1[3*3+i]);
  }
  #pragma unroll
  for (int i=0;i<5;++i){
    xpk[4+i].x = cvtpk_bf16(f2[0*5+i], f2[1*5+i]);
    xpk[4+i].y = cvtpk_bf16(f2[2*5+i], f2[3*5+i]);
  }
}

// general path for one tile: per i: T = x-plane_i @ W_p (2 MFMA), immediately consumed vs yc
template<int G,int L1,int L3>
__device__ __forceinline__ void gen_path(const unsigned short* s_xt,
                                         bf16x8 b0, bf16x8 b1,
                                         const float* yg4, f32x4* acc, int cl, int q){
  constexpr int D1=2*L1+1, D3=2*L3+1;
  constexpr int PB = (L1==0)?0:(L1==1)?1:4;
  const f32x4 z4 = {0.f,0.f,0.f,0.f};
  #pragma unroll
  for (int i=0;i<D1;++i){
    bf16x8 a0 = afrag(s_xt, PB+i, 0, cl, q);
    bf16x8 a1 = afrag(s_xt, PB+i, 1, cl, q);
    f32x4 T = __builtin_amdgcn_mfma_f32_16x16x32_bf16(a0, b0, z4, 0,0,0);
    T       = __builtin_amdgcn_mfma_f32_16x16x32_bf16(a1, b1, T,  0,0,0);
    #pragma unroll
    for (int k=0;k<D3;++k){
      f32x4 yv = *reinterpret_cast<const f32x4*>(yg4 + (GB[G] + i*D3 + k)*16);
      acc[KKB[L3]+k] += T*yv;
    }
  }
}

// delta paths (exact CG structure), one tile each
template<int PLANE0,int D1,int ACCB>  // (l,0,l): acc[ACCB+i] += (c*y0)*T_i
__device__ __forceinline__ void delta_l0(const unsigned short* s_xt, bf16x8 b0, bf16x8 b1,
                                         f32x4 cy, f32x4* acc, int cl, int q){
  const f32x4 z4 = {0.f,0.f,0.f,0.f};
  #pragma unroll
  for (int i=0;i<D1;++i){
    bf16x8 a0 = afrag(s_xt, PLANE0+i, 0, cl, q);
    bf16x8 a1 = afrag(s_xt, PLANE0+i, 1, cl, q);
    f32x4 T = __builtin_amdgcn_mfma_f32_16x16x32_bf16(a0, b0, z4, 0,0,0);
    T       = __builtin_amdgcn_mfma_f32_16x16x32_bf16(a1, b1, T,  0,0,0);
    acc[ACCB+i] += cy*T;
  }
}
template<int D3,int YE>  // (0,l,l): acc[KKB+k] += c*y[YE+k]*T (single plane 0)
__device__ __forceinline__ void delta_0l(const unsigned short* s_xt, bf16x8 b0, bf16x8 b1,
                                         float c, const float* yg4, f32x4* acc, int accb,
                                         int cl, int q){
  const f32x4 z4 = {0.f,0.f,0.f,0.f};
  bf16x8 a0 = afrag(s_xt, 0, 0, cl, q);
  bf16x8 a1 = afrag(s_xt, 0, 1, cl, q);
  f32x4 T = __builtin_amdgcn_mfma_f32_16x16x32_bf16(a0, b0, z4, 0,0,0);
  T       = __builtin_amdgcn_mfma_f32_16x16x32_bf16(a1, b1, T,  0,0,0);
  #pragma unroll
  for (int k=0;k<D3;++k){
    f32x4 yv = *reinterpret_cast<const f32x4*>(yg4 + (YE+k)*16);
    acc[accb+k] += (c*yv)*T;
  }
}
template<int PLANE0,int D1,int YE>  // (l,l,0): acc[0] += c * sum_i y[YE+i]*T_i
__device__ __forceinline__ void delta_ll0(const unsigned short* s_xt, bf16x8 b0, bf16x8 b1,
                                          float c, const float* yg4, f32x4* acc,
                                          int cl, int q){
  const f32x4 z4 = {0.f,0.f,0.f,0.f};
  f32x4 s = z4;
  #pragma unroll
  for (int i=0;i<D1;++i){
    bf16x8 a0 = afrag(s_xt, PLANE0+i, 0, cl, q);
    bf16x8 a1 = afrag(s_xt, PLANE0+i, 1, cl, q);
    f32x4 T = __builtin_amdgcn_mfma_f32_16x16x32_bf16(a0, b0, z4, 0,0,0);
    T       = __builtin_amdgcn_mfma_f32_16x16x32_bf16(a1, b1, T,  0,0,0);
    f32x4 yv = *reinterpret_cast<const f32x4*>(yg4 + (YE+i)*16);
    s += yv*T;
  }
  acc[0] += s*c;
}

__device__ __forceinline__ void epilogue(const f32x4* acc, float* __restrict__ out,
                                         int base, int wid, int cl, int q){
  const int wc = wid*16 + cl;
  #pragma unroll
  for (int r=0;r<4;++r){
    float* orow = out + (size_t)(base + q*4 + r)*576;
    orow[wc] = acc[0][r];
    #pragma unroll
    for (int k=0;k<3;++k) orow[64 + wc*3 + k]  = acc[1+k][r];
    #pragma unroll
    for (int k=0;k<5;++k) orow[256 + wc*5 + k] = acc[4+k][r];
  }
}

// stage one 16-row tile's x into LDS + compute its yc (register y) — no barriers inside
__device__ __forceinline__ void stage_tile(const float* __restrict__ x, const float* __restrict__ y,
                                           int nbase, unsigned short* s_xt, float* s_yg,
                                           const CGArg& cga, int tid, int n_s, int t16,
                                           bool ywriter){
  const float* xb = x + (size_t)(nbase + n_s)*576;
  float4 r0 = *reinterpret_cast<const float4*>(xb + t16*4);
  float4 r1[3], r2[5];
  #pragma unroll
  for (int i=0;i<3;++i) r1[i] = *reinterpret_cast<const float4*>(xb + 64 + t16*12 + 4*i);
  #pragma unroll
  for (int i=0;i<5;++i) r2[i] = *reinterpret_cast<const float4*>(xb + 256 + t16*20 + 4*i);

  float yl[9];
  {
    const float* yrow = y + (size_t)(nbase + t16)*9;
    #pragma unroll
    for (int j=0;j<9;++j) yl[j] = yrow[j];
  }

  uint2 xpk[9];
  pack_x(r0, r1, r2, xpk);
  #pragma unroll
  for (int pl=0; pl<9; ++pl) xt_write_pk(s_xt, pl, n_s, t16, xpk[pl]);

  if (ywriter){
    #pragma unroll
    for (int j=0;j<9;++j) s_yg[(128+j)*16 + t16] = yl[j];
  }

  #pragma unroll
  for (int g=0; g<8; ++g){
    constexpr int GPp[8] = {5,6,7,8,10,11,13,14};
    const int p = GPp[g];
    const int d1=2*PL1[p]+1, d2=2*PL2[p]+1, d3=2*PL3[p]+1;
    const int cnt = d1*d3*16;
    for (int idx=tid; idx<cnt; idx+=256){
      int ik = idx >> 4;
      int i  = ik/d3;
      int k  = ik - i*d3;
      float s=0.f;
      for (int j=0;j<d2;++j)
        s += yl[YOFF[PL2[p]]+j]*cga.v[CGOFF[p]+(i*d2+j)*d3+k];
      s_yg[(GB[g]+ik)*16 + t16] = s;
    }
  }
}

__global__ __launch_bounds__(256, 2)
void tp_kernel(const float* __restrict__ x, const float* __restrict__ y,
               const unsigned short* __restrict__ WT, float* __restrict__ out, CGArg cga)
{
  __shared__ __align__(16) unsigned short s_xt[2*9*16*64];  // 36864 B (two 16-row tiles)
  __shared__ __align__(16) float s_yg[2*YGTOT*16];          // 17536 B

  const int tid = threadIdx.x;
  const int n0 = blockIdx.x * 32;
  const int n_s = tid>>4, t16 = tid&15;
  const int lane = tid & 63, wid = tid >> 6;
  const int cl = lane & 15, q = lane >> 4;

  unsigned short* s_xt1 = s_xt + 9*16*64;
  float* s_yg1 = s_yg + YGTOT*16;

  // ---- phase A: stage both tiles (single barrier after) ----
  stage_tile(x, y, n0,    s_xt,  s_yg,  cga, tid, n_s, t16, tid<16);
  stage_tile(x, y, n0+16, s_xt1, s_yg1, cga, tid, n_s, t16, tid>=16 && tid<32);
  __syncthreads();

  // ---- phase B: MFMA + consume, no barriers; both tiles share b-frags ----
  const float* yg40 = s_yg  + q*4;
  const float* yg41 = s_yg1 + q*4;
  #define YV0(E) (*reinterpret_cast<const f32x4*>(yg40 + (E)*16))
  #define YV1(E) (*reinterpret_cast<const f32x4*>(yg41 + (E)*16))

  const f32x4 z4 = {0.f,0.f,0.f,0.f};
  f32x4 acc0[9] = {z4,z4,z4,z4,z4,z4,z4,z4,z4};
  f32x4 acc1[9] = {z4,z4,z4,z4,z4,z4,z4,z4,z4};
  bf16x8 b0,b1,nb0,nb1;
  const f32x4 y0v0 = YV0(128), y0v1 = YV1(128);

  #define LDB(P) { nb0 = wfrag(WT,P,wid,cl,0,q); nb1 = wfrag(WT,P,wid,cl,1,q); }
  #define ADV    { b0 = nb0; b1 = nb1; }

  b0 = wfrag(WT,0,wid,cl,0,q); b1 = wfrag(WT,0,wid,cl,1,q);

  // p0 (0,0,0): delta_l0 with D1=1, plane 0, acc base 0
  LDB(1);
  delta_l0<0,1,0>(s_xt,  b0,b1, cga.v[CGOFF[0]]*y0v0, acc0, cl,q);
  delta_l0<0,1,0>(s_xt1, b0,b1, cga.v[CGOFF[0]]*y0v1, acc1, cl,q);
  ADV;
  // p1 (0,1,1)
  LDB(2);
  delta_0l<3,129>(s_xt,  b0,b1, cga.v[CGOFF[1]], yg40, acc0, 1, cl,q);
  delta_0l<3,129>(s_xt1, b0,b1, cga.v[CGOFF[1]], yg41, acc1, 1, cl,q);
  ADV;
  // p2 (0,2,2)
  LDB(3);
  delta_0l<5,132>(s_xt,  b0,b1, cga.v[CGOFF[2]], yg40, acc0, 4, cl,q);
  delta_0l<5,132>(s_xt1, b0,b1, cga.v[CGOFF[2]], yg41, acc1, 4, cl,q);
  ADV;
  // p3 (1,0,1): planes 1..3, acc base 1
  LDB(4);
  delta_l0<1,3,1>(s_xt,  b0,b1, cga.v[CGOFF[3]]*y0v0, acc0, cl,q);
  delta_l0<1,3,1>(s_xt1, b0,b1, cga.v[CGOFF[3]]*y0v1, acc1, cl,q);
  ADV;
  // p4 (1,1,0): planes 1..3, y entries 129..131
  LDB(5);
  delta_ll0<1,3,129>(s_xt,  b0,b1, cga.v[CGOFF[4]], yg40, acc0, cl,q);
  delta_ll0<1,3,129>(s_xt1, b0,b1, cga.v[CGOFF[4]], yg41, acc1, cl,q);
  ADV;
  LDB(6);
  gen_path<0,1,1>(s_xt,  b0,b1, yg40, acc0, cl,q);   // p5 (1,1,1)
  gen_path<0,1,1>(s_xt1, b0,b1, yg41, acc1, cl,q);
  ADV;
  LDB(7);
  gen_path<1,1,2>(s_xt,  b0,b1, yg40, acc0, cl,q);   // p6 (1,1,2)
  gen_path<1,1,2>(s_xt1, b0,b1, yg41, acc1, cl,q);
  ADV;
  LDB(8);
  gen_path<2,1,1>(s_xt,  b0,b1, yg40, acc0, cl,q);   // p7 (1,2,1)
  gen_path<2,1,1>(s_xt1, b0,b1, yg41, acc1, cl,q);
  ADV;
  LDB(9);
  gen_path<3,1,2>(s_xt,  b0,b1, yg40, acc0, cl,q);   // p8 (1,2,2)
  gen_path<3,1,2>(s_xt1, b0,b1, yg41, acc1, cl,q);
  ADV;
  // p9 (2,0,2): planes 4..8, acc base 4
  LDB(10);
  delta_l0<4,5,4>(s_xt,  b0,b1, cga.v[CGOFF[9]]*y0v0, acc0, cl,q);
  delta_l0<4,5,4>(s_xt1, b0,b1, cga.v[CGOFF[9]]*y0v1, acc1, cl,q);
  ADV;
  LDB(11);
  gen_path<4,2,1>(s_xt,  b0,b1, yg40, acc0, cl,q);   // p10 (2,1,1)
  gen_path<4,2,1>(s_xt1, b0,b1, yg41, acc1, cl,q);
  ADV;
  LDB(12);
  gen_path<5,2,2>(s_xt,  b0,b1, yg40, acc0, cl,q);   // p11 (2,1,2)
  gen_path<5,2,2>(s_xt1, b0,b1, yg41, acc1, cl,q);
  ADV;
  // p12 (2,2,0): planes 4..8, y entries 132..136
  LDB(13);
  delta_ll0<4,5,132>(s_xt,  b0,b1, cga.v[CGOFF[12]], yg40, acc0, cl,q);
  delta_ll0<4,5,132>(s_xt1, b0,b1, cga.v[CGOFF[12]], yg41, acc1, cl,q);
  ADV;
  LDB(14);
  gen_path<6,2,1>(s_xt,  b0,b1, yg40, acc0, cl,q);   // p13 (2,2,1)
  gen_path<6,2,1>(s_xt1, b0,b1, yg41, acc1, cl,q);
  ADV;
  gen_path<7,2,2>(s_xt,  b0,b1, yg40, acc0, cl,q);   // p14 (2,2,2)
  gen_path<7,2,2>(s_xt1, b0,b1, yg41, acc1, cl,q);

  #undef LDB
  #undef ADV
  #undef YV0
  #undef YV1

  epilogue(acc0, out, n0,    wid, cl, q);
  epilogue(acc1, out, n0+16, wid, cl, q);
}

// W[p][u][w] (fp32) -> WT[p][w][u] (bf16, RNE) once per launch
__global__ void wt_kernel(const float* __restrict__ W, unsigned short* __restrict__ WT){
  int t = blockIdx.x*256 + threadIdx.x;      // 61440 total
  int p = t >> 12, r = t & 4095, w = r >> 6, u = r & 63;
  float f = W[(p<<12) + (u<<6) + w];
  unsigned fu = __builtin_bit_cast(unsigned, f);
  unsigned rr = (fu + 0x7FFFu + ((fu>>16)&1u)) >> 16;
  WT[t] = (unsigned short)rr;
}

// ---------------- launch ----------------
extern "C" void kernel_launch(void* const* d_in, const int* in_sizes, int n_in,
                              void* d_out, int out_size, void* d_ws, size_t ws_size,
                              hipStream_t stream) {
  const float* x = (const float*)d_in[0];
  const float* y = (const float*)d_in[1];
  const float* W = (const float*)d_in[2];
  float* out = (float*)d_out;
  (void)in_sizes; (void)n_in; (void)out_size; (void)ws_size;

  unsigned short* WT = (unsigned short*)d_ws;   // 61440 * 2 B

  CGArg cga;
  compute_cg(cga.v);

  hipLaunchKernelGGL(wt_kernel, dim3(240), dim3(256), 0, stream, W, WT);
  hipLaunchKernelGGL(tp_kernel, dim3(1024), dim3(256), 0, stream, x, y, WT, out, cga);
}